// Round 4
// baseline (1153.645 us; speedup 1.0000x reference)
//
#include <hip/hip_runtime.h>
#include <stdint.h>

#define N_NODES 32768
#define N_EDGES 262144
#define NB 8
#define TW 25

typedef __attribute__((ext_vector_type(8))) short short8;
typedef __attribute__((ext_vector_type(4))) float floatx4;

__device__ __forceinline__ float swishf(float x) { return x / (1.0f + __expf(-x)); }

__device__ __forceinline__ unsigned short f2bf(float x) {
    union { float f; unsigned u; } v; v.f = x;
    unsigned r = v.u + 0x7FFFu + ((v.u >> 16) & 1u);
    return (unsigned short)(r >> 16);
}
__device__ __forceinline__ float bf2f(unsigned short b) {
    union { unsigned u; float f; } v; v.u = ((unsigned)b) << 16; return v.f;
}

// ---------------------------------------------------------------------------
__global__ void init_kernel(const float* __restrict__ pos,
                            float* __restrict__ posx, float* __restrict__ post) {
    int i = blockIdx.x * 256 + threadIdx.x;
    if (i < N_NODES) {
        post[i] = pos[i * 2 + 0] * 0.25f;
        posx[i] = pos[i * 2 + 1] * 0.0625f;
    }
}

__global__ void deg_kernel(const int* __restrict__ tgt, int* __restrict__ deg) {
    int i = blockIdx.x * 256 + threadIdx.x;
    if (i < N_EDGES) atomicAdd(&deg[tgt[i]], 1);
}

__global__ __launch_bounds__(1024) void scan_kernel(const int* __restrict__ deg,
                                                    int* __restrict__ rowptr,
                                                    int* __restrict__ cursor) {
    __shared__ int ps[1024];
    int t = threadIdx.x;
    int base = t * 32;
    int tot = 0;
    for (int i = 0; i < 32; ++i) tot += deg[base + i];
    ps[t] = tot;
    __syncthreads();
    for (int off = 1; off < 1024; off <<= 1) {
        int v = (t >= off) ? ps[t - off] : 0;
        __syncthreads();
        ps[t] += v;
        __syncthreads();
    }
    int run = ps[t] - tot;
    for (int i = 0; i < 32; ++i) {
        rowptr[base + i] = run;
        cursor[base + i] = run;
        run += deg[base + i];
    }
    if (t == 1023) rowptr[N_NODES] = run;
}

__global__ void scatter_kernel(const int* __restrict__ tgt, int* __restrict__ cursor,
                               int* __restrict__ perm) {
    int i = blockIdx.x * 256 + threadIdx.x;
    if (i < N_EDGES) {
        int p = atomicAdd(&cursor[tgt[i]], 1);
        perm[p] = i;
    }
}

// ---------------------------------------------------------------------------
// Pack weight into MFMA B-frag order: frag id = ((l*Kc + c)*8 + t8)*64 + lane,
// lane holds B[k=c*32+(lane>>4)*8+j][n=t8*16+(lane&15)], j=0..7.
__global__ __launch_bounds__(256) void pack_kernel(const float* __restrict__ W,
                                                   unsigned short* __restrict__ Wp,
                                                   int Kreal, int Kc, int total) {
    int id = blockIdx.x * 256 + threadIdx.x;
    if (id >= total) return;
    int lane = id & 63;
    int t8 = (id >> 6) & 7;
    int rest = id >> 9;
    int c = rest % Kc;
    int l = rest / Kc;
    int n = t8 * 16 + (lane & 15);
    int kb = c * 32 + (lane >> 4) * 8;
    short8 v;
    #pragma unroll
    for (int j = 0; j < 8; ++j) {
        int k = kb + j;
        float x = (k < Kreal) ? W[((size_t)l * Kreal + k) * 128 + n] : 0.f;
        v[j] = (short)f2bf(x);
    }
    *(short8*)(Wp + (size_t)id * 8) = v;
}

// ---------------------------------------------------------------------------
__global__ __launch_bounds__(256) void encoder_kernel(
    const float* __restrict__ u, const float* __restrict__ posx,
    const float* __restrict__ post,
    const float* __restrict__ We1, const float* __restrict__ be1,
    const float* __restrict__ We2, const float* __restrict__ be2,
    float* __restrict__ h, unsigned short* __restrict__ h_bf)
{
    __shared__ __align__(16) float As[64 * 36];
    __shared__ __align__(16) float Ws[32 * 128];
    __shared__ __align__(16) float Ms[64 * 128];

    int t = threadIdx.x;
    int n0 = blockIdx.x * 64;
    int rg = t >> 5, cg = t & 31;

    float acc[8][4] = {};
    {
        int kk = t >> 3, cb = (t & 7) * 16;
        #pragma unroll
        for (int j = 0; j < 4; ++j) {
            float4 w = make_float4(0.f, 0.f, 0.f, 0.f);
            if (kk < 27) w = *(const float4*)&We1[kk * 128 + cb + j * 4];
            *(float4*)&Ws[kk * 128 + cb + j * 4] = w;
        }
        int el = t >> 2, kb = (t & 3) * 8, n = n0 + el;
        float v[8];
        #pragma unroll
        for (int j = 0; j < 8; ++j) {
            int k = kb + j;
            float x = 0.f;
            if (k < 25) x = u[n * 25 + k];
            else if (k == 25) x = posx[n];
            else if (k == 26) x = post[n];
            v[j] = x;
        }
        #pragma unroll
        for (int j = 0; j < 8; j += 4)
            *(float4*)&As[el * 36 + kb + j] = make_float4(v[j], v[j+1], v[j+2], v[j+3]);
        __syncthreads();
        #pragma unroll 4
        for (int kk2 = 0; kk2 < 32; ++kk2) {
            float4 b = *(const float4*)&Ws[kk2 * 128 + cg * 4];
            float a[8];
            #pragma unroll
            for (int i = 0; i < 8; ++i) a[i] = As[(rg * 8 + i) * 36 + kk2];
            #pragma unroll
            for (int i = 0; i < 8; ++i) {
                acc[i][0] += a[i] * b.x; acc[i][1] += a[i] * b.y;
                acc[i][2] += a[i] * b.z; acc[i][3] += a[i] * b.w;
            }
        }
        __syncthreads();
    }
    {
        float4 b1 = *(const float4*)&be1[cg * 4];
        #pragma unroll
        for (int i = 0; i < 8; ++i) {
            float4 m;
            m.x = swishf(acc[i][0] + b1.x);
            m.y = swishf(acc[i][1] + b1.y);
            m.z = swishf(acc[i][2] + b1.z);
            m.w = swishf(acc[i][3] + b1.w);
            *(float4*)&Ms[(rg * 8 + i) * 128 + cg * 4] = m;
        }
        __syncthreads();
    }
    float acc2[8][4] = {};
    for (int k0 = 0; k0 < 128; k0 += 32) {
        int kk = t >> 3, cb = (t & 7) * 16;
        #pragma unroll
        for (int j = 0; j < 4; ++j)
            *(float4*)&Ws[kk * 128 + cb + j * 4] =
                *(const float4*)&We2[(k0 + kk) * 128 + cb + j * 4];
        __syncthreads();
        #pragma unroll 4
        for (int kk2 = 0; kk2 < 32; ++kk2) {
            float4 b = *(const float4*)&Ws[kk2 * 128 + cg * 4];
            float a[8];
            #pragma unroll
            for (int i = 0; i < 8; ++i) a[i] = Ms[(rg * 8 + i) * 128 + (k0 + kk2)];
            #pragma unroll
            for (int i = 0; i < 8; ++i) {
                acc2[i][0] += a[i] * b.x; acc2[i][1] += a[i] * b.y;
                acc2[i][2] += a[i] * b.z; acc2[i][3] += a[i] * b.w;
            }
        }
        __syncthreads();
    }
    {
        float4 b2 = *(const float4*)&be2[cg * 4];
        #pragma unroll
        for (int i = 0; i < 8; ++i) {
            int n = n0 + rg * 8 + i;
            float4 o;
            o.x = swishf(acc2[i][0] + b2.x);
            o.y = swishf(acc2[i][1] + b2.y);
            o.z = swishf(acc2[i][2] + b2.z);
            o.w = swishf(acc2[i][3] + b2.w);
            *(float4*)&h[(size_t)n * 128 + cg * 4] = o;
            unsigned short* hb = h_bf + (size_t)n * 128 + cg * 4;
            uint2 pk;
            pk.x = (unsigned)f2bf(o.x) | ((unsigned)f2bf(o.y) << 16);
            pk.y = (unsigned)f2bf(o.z) | ((unsigned)f2bf(o.w) << 16);
            *(uint2*)hb = pk;
        }
    }
}

// ---------------------------------------------------------------------------
// Message MLP, round-4 structure:
//  - block = 64 tgt-sorted edges, 4 waves; wave covers 32 rows x 64 cols:
//      rows (w&1)*32 .. +32, tiles (w>>1)*4 .. +4
//  - A-fragments loaded DIRECTLY from global h_bf / computed from u
//    (h_bf row layout == A-frag layout) -> no A staging, no Cs, 2 barriers
//  - GEMM1 -> swish -> Ms (LDS, C->A transpose) -> GEMM2 -> in-register
//    run-reduction over each lane's 4 sorted rows -> fp32 atomics into agg
__global__ __launch_bounds__(256, 4) void message_kernel(
    const unsigned short* __restrict__ h_bf, const float* __restrict__ u,
    const float* __restrict__ posx, const float* __restrict__ post,
    const int* __restrict__ src, const int* __restrict__ tgt,
    const int* __restrict__ perm,
    const unsigned short* __restrict__ W1p, const float* __restrict__ b1,
    const unsigned short* __restrict__ W2p, const float* __restrict__ b2,
    float* __restrict__ agg)
{
    __shared__ __align__(16) unsigned short Ms[64 * 136];  // 17408 B
    __shared__ int srcS[64], tgtS[64];

    int t = threadIdx.x;
    int e0 = blockIdx.x * 64;
    if (t < 64) {
        int e = perm[e0 + t];
        srcS[t] = src[e]; tgtS[t] = tgt[e];
    }
    __syncthreads();

    int w = t >> 6, lane = t & 63, q = lane >> 4, m = lane & 15;
    int g0 = (w & 1) * 2;      // M-group base (16-row groups): rows g0*16..g0*16+31
    int tb = (w >> 1) * 4;     // N-tile base: cols tb*16..tb*16+63

    int row0 = g0 * 16 + m;
    int row1 = row0 + 16;
    int tg0 = tgtS[row0], sr0 = srcS[row0];
    int tg1 = tgtS[row1], sr1 = srcS[row1];

    // ---- diff fragments (K-chunk 8) computed per lane
    short8 d0, d1;
    {
        float uv0[8], uv1[8];
        #pragma unroll
        for (int j = 0; j < 8; ++j) { uv0[j] = 0.f; uv1[j] = 0.f; }
        if (q < 3) {
            #pragma unroll
            for (int j = 0; j < 8; ++j) {
                int k = q * 8 + j;
                if (k < 24) {
                    uv0[j] = u[(size_t)tg0 * 25 + k] - u[(size_t)sr0 * 25 + k];
                    uv1[j] = u[(size_t)tg1 * 25 + k] - u[(size_t)sr1 * 25 + k];
                }
            }
        } else {
            uv0[0] = u[(size_t)tg0 * 25 + 24] - u[(size_t)sr0 * 25 + 24];
            uv0[1] = posx[tg0] - posx[sr0];
            uv0[2] = post[tg0];
            uv1[0] = u[(size_t)tg1 * 25 + 24] - u[(size_t)sr1 * 25 + 24];
            uv1[1] = posx[tg1] - posx[sr1];
            uv1[2] = post[tg1];
        }
        // k=24 for q=3 handled above; for q<3 chunk covers k=0..23 only when k<24
        if (q == 2) {  // k = 16..23 all < 24: already covered by k<24 branch
        }
        #pragma unroll
        for (int j = 0; j < 8; ++j) { d0[j] = (short)f2bf(uv0[j]); d1[j] = (short)f2bf(uv1[j]); }
    }
    // fix q==2 case covers k=16..23 (<24, fine); q==0,1 fine; u[24] only in q==3 path.

    // ---- GEMM1: K=288 (9 chunks), 2 M-groups x 4 N-tiles
    floatx4 acc[2][4] = {};
    const short8* HB = (const short8*)h_bf;  // 16B units; row = 16 units
    #pragma unroll
    for (int c = 0; c < 9; ++c) {
        short8 a0, a1;
        if (c < 4) {
            a0 = HB[(size_t)tg0 * 16 + c * 4 + q];
            a1 = HB[(size_t)tg1 * 16 + c * 4 + q];
        } else if (c < 8) {
            a0 = HB[(size_t)sr0 * 16 + (c - 4) * 4 + q];
            a1 = HB[(size_t)sr1 * 16 + (c - 4) * 4 + q];
        } else {
            a0 = d0; a1 = d1;
        }
        #pragma unroll
        for (int tt = 0; tt < 4; ++tt) {
            short8 b = *(const short8*)(W1p + ((size_t)(c * 8 + tb + tt) * 64 + lane) * 8);
            acc[0][tt] = __builtin_amdgcn_mfma_f32_16x16x32_bf16(a0, b, acc[0][tt], 0, 0, 0);
            acc[1][tt] = __builtin_amdgcn_mfma_f32_16x16x32_bf16(a1, b, acc[1][tt], 0, 0, 0);
        }
    }

    // ---- epilogue 1: bias+swish -> Ms (C-layout rows q*4+r, col tile*16+m)
    #pragma unroll
    for (int tt = 0; tt < 4; ++tt) {
        float bv = b1[(tb + tt) * 16 + m];
        #pragma unroll
        for (int r = 0; r < 4; ++r) {
            Ms[(g0 * 16 + q * 4 + r) * 136 + (tb + tt) * 16 + m]       = f2bf(swishf(acc[0][tt][r] + bv));
            Ms[((g0 + 1) * 16 + q * 4 + r) * 136 + (tb + tt) * 16 + m] = f2bf(swishf(acc[1][tt][r] + bv));
        }
    }
    __syncthreads();

    // ---- GEMM2: K=128 (4 chunks)
    floatx4 acc2[2][4] = {};
    #pragma unroll
    for (int c = 0; c < 4; ++c) {
        short8 a0 = *(const short8*)(&Ms[row0 * 136 + c * 32 + q * 8]);
        short8 a1 = *(const short8*)(&Ms[row1 * 136 + c * 32 + q * 8]);
        #pragma unroll
        for (int tt = 0; tt < 4; ++tt) {
            short8 b = *(const short8*)(W2p + ((size_t)(c * 8 + tb + tt) * 64 + lane) * 8);
            acc2[0][tt] = __builtin_amdgcn_mfma_f32_16x16x32_bf16(a0, b, acc2[0][tt], 0, 0, 0);
            acc2[1][tt] = __builtin_amdgcn_mfma_f32_16x16x32_bf16(a1, b, acc2[1][tt], 0, 0, 0);
        }
    }

    // ---- epilogue 2: swish + in-register run-reduction over 4 sorted rows
    int tgr[2][4];
    #pragma unroll
    for (int g = 0; g < 2; ++g)
        #pragma unroll
        for (int r = 0; r < 4; ++r)
            tgr[g][r] = tgtS[(g0 + g) * 16 + q * 4 + r];
    #pragma unroll
    for (int g = 0; g < 2; ++g) {
        #pragma unroll
        for (int tt = 0; tt < 4; ++tt) {
            int col = (tb + tt) * 16 + m;
            float bv = b2[col];
            float run = swishf(acc2[g][tt][0] + bv);
            int prev = tgr[g][0];
            #pragma unroll
            for (int r = 1; r < 4; ++r) {
                float v = swishf(acc2[g][tt][r] + bv);
                if (tgr[g][r] != prev) {
                    atomicAdd(&agg[(size_t)prev * 128 + col], run);
                    run = v; prev = tgr[g][r];
                } else {
                    run += v;
                }
            }
            atomicAdd(&agg[(size_t)prev * 128 + col], run);
        }
    }
}

// ---------------------------------------------------------------------------
// Update MLP + fused batch-stats accumulation.
__global__ __launch_bounds__(256) void update_kernel(
    float* __restrict__ h, const unsigned short* __restrict__ h_bf,
    const float* __restrict__ agg, const int* __restrict__ deg,
    const float* __restrict__ post,
    const unsigned short* __restrict__ W1p, const float* __restrict__ b1,
    const unsigned short* __restrict__ W2p, const float* __restrict__ b2,
    float* __restrict__ stats)
{
    __shared__ unsigned short Ms[64 * 136];
    int t = threadIdx.x;
    int n0 = blockIdx.x * 64;
    int w = t >> 6, lane = t & 63, q = lane >> 4, m = lane & 15;
    int n = n0 + w * 16 + m;

    short8 afr[9];
    {
        const short8* hn = (const short8*)(h_bf + (size_t)n * 128);
        #pragma unroll
        for (int c = 0; c < 4; ++c) afr[c] = hn[c * 4 + q];
        float ic = 1.0f / fmaxf((float)deg[n], 1.0f);
        #pragma unroll
        for (int c = 0; c < 4; ++c) {
            const float* ap = agg + (size_t)n * 128 + c * 32 + q * 8;
            short8 a;
            #pragma unroll
            for (int j = 0; j < 8; ++j) a[j] = (short)f2bf(ap[j] * ic);
            afr[4 + c] = a;
        }
        short8 a8;
        #pragma unroll
        for (int j = 0; j < 8; ++j) a8[j] = 0;
        if (q == 0) a8[0] = (short)f2bf(post[n]);  // k=256
        afr[8] = a8;
    }

    floatx4 acc[8] = {};
    #pragma unroll
    for (int c = 0; c < 9; ++c) {
        const short8* Bp = (const short8*)(W1p) + (size_t)(c * 8) * 64 + lane;
        #pragma unroll
        for (int t8 = 0; t8 < 8; ++t8) {
            short8 b = Bp[t8 * 64];
            acc[t8] = __builtin_amdgcn_mfma_f32_16x16x32_bf16(afr[c], b, acc[t8], 0, 0, 0);
        }
    }
    #pragma unroll
    for (int t8 = 0; t8 < 8; ++t8) {
        float bv = b1[t8 * 16 + m];
        #pragma unroll
        for (int r = 0; r < 4; ++r)
            Ms[(w * 16 + q * 4 + r) * 136 + t8 * 16 + m] = f2bf(swishf(acc[t8][r] + bv));
    }
    __syncthreads();
    short8 a2[4];
    #pragma unroll
    for (int c = 0; c < 4; ++c)
        a2[c] = *(const short8*)(&Ms[(w * 16 + m) * 136 + c * 32 + q * 8]);

    floatx4 acc2[8] = {};
    #pragma unroll
    for (int c = 0; c < 4; ++c) {
        const short8* Bp = (const short8*)(W2p) + (size_t)(c * 8) * 64 + lane;
        #pragma unroll
        for (int t8 = 0; t8 < 8; ++t8) {
            short8 b = Bp[t8 * 64];
            acc2[t8] = __builtin_amdgcn_mfma_f32_16x16x32_bf16(a2[c], b, acc2[t8], 0, 0, 0);
        }
    }
    int bidx = n0 >> 12;
    #pragma unroll
    for (int t8 = 0; t8 < 8; ++t8) {
        float bv = b2[t8 * 16 + m];
        float s = 0.f, s2 = 0.f;
        #pragma unroll
        for (int r = 0; r < 4; ++r) {
            size_t idx = (size_t)(n0 + w * 16 + q * 4 + r) * 128 + t8 * 16 + m;
            float hv = h[idx] + swishf(acc2[t8][r] + bv);
            h[idx] = hv;
            s += hv; s2 += hv * hv;
        }
        s  += __shfl_xor(s, 16);  s  += __shfl_xor(s, 32);
        s2 += __shfl_xor(s2, 16); s2 += __shfl_xor(s2, 32);
        if (q == 0) {
            atomicAdd(&stats[bidx * 128 + t8 * 16 + m], s);
            atomicAdd(&stats[(NB + bidx) * 128 + t8 * 16 + m], s2);
        }
    }
}

// ---------------------------------------------------------------------------
__global__ __launch_bounds__(256) void norm_kernel(float* __restrict__ h,
                                                   unsigned short* __restrict__ h_bf,
                                                   const float* __restrict__ stats) {
    size_t idx = (size_t)blockIdx.x * 256 + threadIdx.x;
    int n = (int)(idx >> 7), c = (int)(idx & 127);
    int b = n >> 12;
    float mean = stats[b * 128 + c] * (1.f / 4096.f);
    float var = stats[(NB + b) * 128 + c] * (1.f / 4096.f) - mean * mean;
    float v = h[idx];
    float r = (v - mean) * rsqrtf(var + 1e-5f);
    h[idx] = r;
    h_bf[idx] = f2bf(r);
}

// ---------------------------------------------------------------------------
__global__ __launch_bounds__(64) void conv_kernel(
    const float* __restrict__ h, const float* __restrict__ u,
    const float* __restrict__ Wc1, const float* __restrict__ bc1,
    const float* __restrict__ Wc2, const float* __restrict__ bc2,
    float* __restrict__ out)
{
    __shared__ float hs[128];
    __shared__ float c1[8 * 38];
    int n = blockIdx.x;
    int t = threadIdx.x;
    hs[t] = h[(size_t)n * 128 + t];
    hs[t + 64] = h[(size_t)n * 128 + t + 64];
    __syncthreads();
    for (int idx = t; idx < 304; idx += 64) {
        int o = idx / 38, p = idx % 38;
        float s = bc1[o];
        #pragma unroll
        for (int k = 0; k < 16; ++k) s += hs[p * 3 + k] * Wc1[o * 16 + k];
        c1[o * 38 + p] = swishf(s);
    }
    __syncthreads();
    if (t < TW) {
        float s = bc2[0];
        #pragma unroll
        for (int o = 0; o < 8; ++o)
            for (int k = 0; k < 14; ++k)
                s += c1[o * 38 + t + k] * Wc2[o * 14 + k];
        float dt_cum = (float)(t + 1) * (4.0f / 250.0f);
        out[n * TW + t] = u[n * 25 + 24] + dt_cum * s;
    }
}

// ---------------------------------------------------------------------------
extern "C" void kernel_launch(void* const* d_in, const int* in_sizes, int n_in,
                              void* d_out, int out_size, void* d_ws, size_t ws_size,
                              hipStream_t stream)
{
    const float* u   = (const float*)d_in[0];
    const float* pos = (const float*)d_in[1];
    const int*   ei  = (const int*)d_in[2];
    const float* We1 = (const float*)d_in[4];
    const float* be1 = (const float*)d_in[5];
    const float* We2 = (const float*)d_in[6];
    const float* be2 = (const float*)d_in[7];
    const float* Wm1 = (const float*)d_in[8];
    const float* bm1 = (const float*)d_in[9];
    const float* Wm2 = (const float*)d_in[10];
    const float* bm2 = (const float*)d_in[11];
    const float* Wu1 = (const float*)d_in[12];
    const float* bu1 = (const float*)d_in[13];
    const float* Wu2 = (const float*)d_in[14];
    const float* bu2 = (const float*)d_in[15];
    const float* Wc1 = (const float*)d_in[16];
    const float* bc1 = (const float*)d_in[17];
    const float* Wc2 = (const float*)d_in[18];
    const float* bc2 = (const float*)d_in[19];
    float* out = (float*)d_out;

    char* base = (char*)d_ws;
    size_t off = 0;
    auto alloc = [&](size_t bytes) -> char* {
        char* r = base + off;
        off = (off + bytes + 511) & ~(size_t)511;
        return r;
    };
    float*          h      = (float*)alloc((size_t)N_NODES * 128 * 4);
    unsigned short* h_bf   = (unsigned short*)alloc((size_t)N_NODES * 128 * 2);
    float*          agg    = (float*)alloc((size_t)N_NODES * 128 * 4);
    float*          posx   = (float*)alloc(N_NODES * 4);
    float*          post   = (float*)alloc(N_NODES * 4);
    float*          stats  = (float*)alloc(2 * NB * 128 * 4);
    int*            deg    = (int*)alloc(N_NODES * 4);
    int*            rowptr = (int*)alloc((N_NODES + 1) * 4);
    int*            cursor = (int*)alloc(N_NODES * 4);
    int*            perm   = (int*)alloc((size_t)N_EDGES * 4);
    unsigned short* Wm1p   = (unsigned short*)alloc((size_t)6 * 9 * 4096 * 2);
    unsigned short* Wm2p   = (unsigned short*)alloc((size_t)6 * 4 * 4096 * 2);
    unsigned short* Wu1p   = (unsigned short*)alloc((size_t)6 * 9 * 4096 * 2);
    unsigned short* Wu2p   = (unsigned short*)alloc((size_t)6 * 4 * 4096 * 2);
    (void)ws_size;

    const int* srcp = ei;
    const int* tgtp = ei + N_EDGES;

    init_kernel<<<N_NODES / 256, 256, 0, stream>>>(pos, posx, post);
    hipMemsetAsync(deg, 0, N_NODES * sizeof(int), stream);
    deg_kernel<<<N_EDGES / 256, 256, 0, stream>>>(tgtp, deg);
    scan_kernel<<<1, 1024, 0, stream>>>(deg, rowptr, cursor);
    scatter_kernel<<<N_EDGES / 256, 256, 0, stream>>>(tgtp, cursor, perm);
    encoder_kernel<<<N_NODES / 64, 256, 0, stream>>>(u, posx, post, We1, be1, We2, be2, h, h_bf);

    {
        int tot1 = 6 * 9 * 512;
        int tot2 = 6 * 4 * 512;
        pack_kernel<<<(tot1 + 255) / 256, 256, 0, stream>>>(Wm1, Wm1p, 283, 9, tot1);
        pack_kernel<<<(tot2 + 255) / 256, 256, 0, stream>>>(Wm2, Wm2p, 128, 4, tot2);
        pack_kernel<<<(tot1 + 255) / 256, 256, 0, stream>>>(Wu1, Wu1p, 257, 9, tot1);
        pack_kernel<<<(tot2 + 255) / 256, 256, 0, stream>>>(Wu2, Wu2p, 128, 4, tot2);
    }

    for (int l = 0; l < 6; ++l) {
        hipMemsetAsync(agg, 0, (size_t)N_NODES * 128 * sizeof(float), stream);
        hipMemsetAsync(stats, 0, 2 * NB * 128 * sizeof(float), stream);
        message_kernel<<<N_EDGES / 64, 256, 0, stream>>>(
            h_bf, u, posx, post, srcp, tgtp, perm,
            Wm1p + (size_t)l * 9 * 4096, bm1 + l * 128,
            Wm2p + (size_t)l * 4 * 4096, bm2 + l * 128, agg);
        update_kernel<<<N_NODES / 64, 256, 0, stream>>>(
            h, h_bf, agg, deg, post,
            Wu1p + (size_t)l * 9 * 4096, bu1 + l * 128,
            Wu2p + (size_t)l * 4 * 4096, bu2 + l * 128, stats);
        norm_kernel<<<(N_NODES * 128) / 256, 256, 0, stream>>>(h, h_bf, stats);
    }

    conv_kernel<<<N_NODES, 64, 0, stream>>>(h, u, Wc1, bc1, Wc2, bc2, out);
}

// Round 5
// 865.592 us; speedup vs baseline: 1.3328x; 1.3328x over previous
//
#include <hip/hip_runtime.h>
#include <stdint.h>

#define N_NODES 32768
#define N_EDGES 262144
#define NB 8
#define TW 25

typedef __attribute__((ext_vector_type(8))) short short8;
typedef __attribute__((ext_vector_type(4))) float floatx4;

__device__ __forceinline__ float swishf(float x) { return x / (1.0f + __expf(-x)); }

__device__ __forceinline__ unsigned short f2bf(float x) {
    union { float f; unsigned u; } v; v.f = x;
    unsigned r = v.u + 0x7FFFu + ((v.u >> 16) & 1u);
    return (unsigned short)(r >> 16);
}
__device__ __forceinline__ float bf2f(unsigned short b) {
    union { unsigned u; float f; } v; v.u = ((unsigned)b) << 16; return v.f;
}

// ---------------------------------------------------------------------------
__global__ void init_kernel(const float* __restrict__ pos,
                            float* __restrict__ posx, float* __restrict__ post) {
    int i = blockIdx.x * 256 + threadIdx.x;
    if (i < N_NODES) {
        post[i] = pos[i * 2 + 0] * 0.25f;
        posx[i] = pos[i * 2 + 1] * 0.0625f;
    }
}

__global__ void deg_kernel(const int* __restrict__ tgt, int* __restrict__ deg) {
    int i = blockIdx.x * 256 + threadIdx.x;
    if (i < N_EDGES) atomicAdd(&deg[tgt[i]], 1);
}

__global__ __launch_bounds__(1024) void scan_kernel(const int* __restrict__ deg,
                                                    int* __restrict__ rowptr,
                                                    int* __restrict__ cursor) {
    __shared__ int ps[1024];
    int t = threadIdx.x;
    int base = t * 32;
    int tot = 0;
    for (int i = 0; i < 32; ++i) tot += deg[base + i];
    ps[t] = tot;
    __syncthreads();
    for (int off = 1; off < 1024; off <<= 1) {
        int v = (t >= off) ? ps[t - off] : 0;
        __syncthreads();
        ps[t] += v;
        __syncthreads();
    }
    int run = ps[t] - tot;
    for (int i = 0; i < 32; ++i) {
        rowptr[base + i] = run;
        cursor[base + i] = run;
        run += deg[base + i];
    }
    if (t == 1023) rowptr[N_NODES] = run;
}

__global__ void scatter_kernel(const int* __restrict__ tgt, int* __restrict__ cursor,
                               int* __restrict__ perm) {
    int i = blockIdx.x * 256 + threadIdx.x;
    if (i < N_EDGES) {
        int p = atomicAdd(&cursor[tgt[i]], 1);
        perm[p] = i;
    }
}

// ---------------------------------------------------------------------------
// Pack weight into MFMA B-frag order: frag id = ((l*Kc + c)*8 + t8)*64 + lane,
// lane holds B[k=c*32+(lane>>4)*8+j][n=t8*16+(lane&15)], j=0..7.
__global__ __launch_bounds__(256) void pack_kernel(const float* __restrict__ W,
                                                   unsigned short* __restrict__ Wp,
                                                   int Kreal, int Kc, int total) {
    int id = blockIdx.x * 256 + threadIdx.x;
    if (id >= total) return;
    int lane = id & 63;
    int t8 = (id >> 6) & 7;
    int rest = id >> 9;
    int c = rest % Kc;
    int l = rest / Kc;
    int n = t8 * 16 + (lane & 15);
    int kb = c * 32 + (lane >> 4) * 8;
    short8 v;
    #pragma unroll
    for (int j = 0; j < 8; ++j) {
        int k = kb + j;
        float x = (k < Kreal) ? W[((size_t)l * Kreal + k) * 128 + n] : 0.f;
        v[j] = (short)f2bf(x);
    }
    *(short8*)(Wp + (size_t)id * 8) = v;
}

// ---------------------------------------------------------------------------
__global__ __launch_bounds__(256) void encoder_kernel(
    const float* __restrict__ u, const float* __restrict__ posx,
    const float* __restrict__ post,
    const float* __restrict__ We1, const float* __restrict__ be1,
    const float* __restrict__ We2, const float* __restrict__ be2,
    float* __restrict__ h, unsigned short* __restrict__ h_bf)
{
    __shared__ __align__(16) float As[64 * 36];
    __shared__ __align__(16) float Ws[32 * 128];
    __shared__ __align__(16) float Ms[64 * 128];

    int t = threadIdx.x;
    int n0 = blockIdx.x * 64;
    int rg = t >> 5, cg = t & 31;

    float acc[8][4] = {};
    {
        int kk = t >> 3, cb = (t & 7) * 16;
        #pragma unroll
        for (int j = 0; j < 4; ++j) {
            float4 w = make_float4(0.f, 0.f, 0.f, 0.f);
            if (kk < 27) w = *(const float4*)&We1[kk * 128 + cb + j * 4];
            *(float4*)&Ws[kk * 128 + cb + j * 4] = w;
        }
        int el = t >> 2, kb = (t & 3) * 8, n = n0 + el;
        float v[8];
        #pragma unroll
        for (int j = 0; j < 8; ++j) {
            int k = kb + j;
            float x = 0.f;
            if (k < 25) x = u[n * 25 + k];
            else if (k == 25) x = posx[n];
            else if (k == 26) x = post[n];
            v[j] = x;
        }
        #pragma unroll
        for (int j = 0; j < 8; j += 4)
            *(float4*)&As[el * 36 + kb + j] = make_float4(v[j], v[j+1], v[j+2], v[j+3]);
        __syncthreads();
        #pragma unroll 4
        for (int kk2 = 0; kk2 < 32; ++kk2) {
            float4 b = *(const float4*)&Ws[kk2 * 128 + cg * 4];
            float a[8];
            #pragma unroll
            for (int i = 0; i < 8; ++i) a[i] = As[(rg * 8 + i) * 36 + kk2];
            #pragma unroll
            for (int i = 0; i < 8; ++i) {
                acc[i][0] += a[i] * b.x; acc[i][1] += a[i] * b.y;
                acc[i][2] += a[i] * b.z; acc[i][3] += a[i] * b.w;
            }
        }
        __syncthreads();
    }
    {
        float4 b1 = *(const float4*)&be1[cg * 4];
        #pragma unroll
        for (int i = 0; i < 8; ++i) {
            float4 m;
            m.x = swishf(acc[i][0] + b1.x);
            m.y = swishf(acc[i][1] + b1.y);
            m.z = swishf(acc[i][2] + b1.z);
            m.w = swishf(acc[i][3] + b1.w);
            *(float4*)&Ms[(rg * 8 + i) * 128 + cg * 4] = m;
        }
        __syncthreads();
    }
    float acc2[8][4] = {};
    for (int k0 = 0; k0 < 128; k0 += 32) {
        int kk = t >> 3, cb = (t & 7) * 16;
        #pragma unroll
        for (int j = 0; j < 4; ++j)
            *(float4*)&Ws[kk * 128 + cb + j * 4] =
                *(const float4*)&We2[(k0 + kk) * 128 + cb + j * 4];
        __syncthreads();
        #pragma unroll 4
        for (int kk2 = 0; kk2 < 32; ++kk2) {
            float4 b = *(const float4*)&Ws[kk2 * 128 + cg * 4];
            float a[8];
            #pragma unroll
            for (int i = 0; i < 8; ++i) a[i] = Ms[(rg * 8 + i) * 128 + (k0 + kk2)];
            #pragma unroll
            for (int i = 0; i < 8; ++i) {
                acc2[i][0] += a[i] * b.x; acc2[i][1] += a[i] * b.y;
                acc2[i][2] += a[i] * b.z; acc2[i][3] += a[i] * b.w;
            }
        }
        __syncthreads();
    }
    {
        float4 b2 = *(const float4*)&be2[cg * 4];
        #pragma unroll
        for (int i = 0; i < 8; ++i) {
            int n = n0 + rg * 8 + i;
            float4 o;
            o.x = swishf(acc2[i][0] + b2.x);
            o.y = swishf(acc2[i][1] + b2.y);
            o.z = swishf(acc2[i][2] + b2.z);
            o.w = swishf(acc2[i][3] + b2.w);
            *(float4*)&h[(size_t)n * 128 + cg * 4] = o;
            unsigned short* hb = h_bf + (size_t)n * 128 + cg * 4;
            uint2 pk;
            pk.x = (unsigned)f2bf(o.x) | ((unsigned)f2bf(o.y) << 16);
            pk.y = (unsigned)f2bf(o.z) | ((unsigned)f2bf(o.w) << 16);
            *(uint2*)hb = pk;
        }
    }
}

// ---------------------------------------------------------------------------
// Message MLP (round-3 structure, round-5 reduction):
//  - block = 64 tgt-sorted edges (perm), 4 waves
//  - A (64 x 288 bf16) staged in LDS once (stride 296)
//  - wave w owns cols [32w,32w+32) over all 64 rows
//  - GEMM1 -> Ms -> GEMM2 -> Cs (LDS bf16)
//  - reduction: thread owns 1 column x 32-row half; complete (interior) tgt
//    runs -> plain coalesced store; boundary-touching runs -> atomicAdd
__global__ __launch_bounds__(256, 4) void message_kernel(
    const unsigned short* __restrict__ h_bf, const float* __restrict__ u,
    const float* __restrict__ posx, const float* __restrict__ post,
    const int* __restrict__ src, const int* __restrict__ tgt,
    const int* __restrict__ perm,
    const unsigned short* __restrict__ W1p, const float* __restrict__ b1,
    const unsigned short* __restrict__ W2p, const float* __restrict__ b2,
    float* __restrict__ agg)
{
    __shared__ __align__(16) unsigned short SH[64 * 296];  // 37888 B
    __shared__ int srcS[64], tgtS[64];
    unsigned short* Msh = SH;          // 64 x 136 bf16
    unsigned short* Cs  = SH + 9216;   // byte 18432: 64 x 132 bf16

    int t = threadIdx.x;
    int e0 = blockIdx.x * 64;
    if (t < 64) {
        int e = perm[e0 + t];
        srcS[t] = src[e]; tgtS[t] = tgt[e];
    }
    __syncthreads();

    // ---- stage A into LDS
    {
        int r = t & 63, cseg = t >> 6;
        int g = tgtS[r], s = srcS[r];
        const short8* hg = (const short8*)(h_bf + (size_t)g * 128);
        const short8* hs = (const short8*)(h_bf + (size_t)s * 128);
        #pragma unroll
        for (int j = 0; j < 4; ++j) {
            int chunk = cseg * 4 + j;  // 0..15
            *(short8*)(SH + r * 296 + chunk * 8)       = hg[chunk];
            *(short8*)(SH + r * 296 + 128 + chunk * 8) = hs[chunk];
        }
        int r2 = t >> 2, part = t & 3;
        int gg = tgtS[r2], ss = srcS[r2];
        unsigned short* dst = SH + r2 * 296 + 256 + part * 8;
        if (part < 3) {
            #pragma unroll
            for (int j = 0; j < 8; ++j) {
                int k = part * 8 + j;
                dst[j] = f2bf(u[(size_t)gg * 25 + k] - u[(size_t)ss * 25 + k]);
            }
        } else {
            dst[0] = f2bf(u[(size_t)gg * 25 + 24] - u[(size_t)ss * 25 + 24]);
            dst[1] = f2bf(posx[gg] - posx[ss]);
            dst[2] = f2bf(post[gg]);
            dst[3] = 0; dst[4] = 0; dst[5] = 0; dst[6] = 0; dst[7] = 0;
        }
    }
    __syncthreads();

    int w = t >> 6, lane = t & 63, q = lane >> 4, m = lane & 15;
    int t80 = 2 * w, t81 = 2 * w + 1;

    // ---- GEMM1: K=288 (9 chunks), wave's 2 N-tiles, 4 M-groups
    floatx4 acc0[4] = {}, acc1[4] = {};
    #pragma unroll
    for (int c = 0; c < 9; ++c) {
        short8 b0 = *(const short8*)(W1p + ((size_t)(c * 8 + t80) * 64 + lane) * 8);
        short8 b1f = *(const short8*)(W1p + ((size_t)(c * 8 + t81) * 64 + lane) * 8);
        #pragma unroll
        for (int g2 = 0; g2 < 4; ++g2) {
            short8 a = *(const short8*)(SH + (g2 * 16 + m) * 296 + c * 32 + q * 8);
            acc0[g2] = __builtin_amdgcn_mfma_f32_16x16x32_bf16(a, b0, acc0[g2], 0, 0, 0);
            acc1[g2] = __builtin_amdgcn_mfma_f32_16x16x32_bf16(a, b1f, acc1[g2], 0, 0, 0);
        }
    }
    __syncthreads();  // A region dead; safe to write Ms

    // ---- epilogue 1 -> Ms
    {
        float bv0 = b1[t80 * 16 + m], bv1 = b1[t81 * 16 + m];
        #pragma unroll
        for (int g2 = 0; g2 < 4; ++g2) {
            #pragma unroll
            for (int r = 0; r < 4; ++r) {
                int row = g2 * 16 + q * 4 + r;
                Msh[row * 136 + t80 * 16 + m] = f2bf(swishf(acc0[g2][r] + bv0));
                Msh[row * 136 + t81 * 16 + m] = f2bf(swishf(acc1[g2][r] + bv1));
            }
        }
    }
    __syncthreads();

    // ---- GEMM2: K=128 (4 chunks)
    floatx4 acc2a[4] = {}, acc2b[4] = {};
    #pragma unroll
    for (int c = 0; c < 4; ++c) {
        short8 b0 = *(const short8*)(W2p + ((size_t)(c * 8 + t80) * 64 + lane) * 8);
        short8 b1f = *(const short8*)(W2p + ((size_t)(c * 8 + t81) * 64 + lane) * 8);
        #pragma unroll
        for (int g2 = 0; g2 < 4; ++g2) {
            short8 a = *(const short8*)(Msh + (g2 * 16 + m) * 136 + c * 32 + q * 8);
            acc2a[g2] = __builtin_amdgcn_mfma_f32_16x16x32_bf16(a, b0, acc2a[g2], 0, 0, 0);
            acc2b[g2] = __builtin_amdgcn_mfma_f32_16x16x32_bf16(a, b1f, acc2b[g2], 0, 0, 0);
        }
    }
    // ---- epilogue 2 -> Cs (disjoint region; no barrier before writes)
    {
        float bv0 = b2[t80 * 16 + m], bv1 = b2[t81 * 16 + m];
        #pragma unroll
        for (int g2 = 0; g2 < 4; ++g2) {
            #pragma unroll
            for (int r = 0; r < 4; ++r) {
                int row = g2 * 16 + q * 4 + r;
                Cs[row * 132 + t80 * 16 + m] = f2bf(swishf(acc2a[g2][r] + bv0));
                Cs[row * 132 + t81 * 16 + m] = f2bf(swishf(acc2b[g2][r] + bv1));
            }
        }
    }
    __syncthreads();

    // ---- reduction: col = t&127 over rows [half*32, half*32+32)
    // interior runs (not touching half edges) are COMPLETE sums -> plain store
    // boundary runs -> atomicAdd (other half/block contributes the rest)
    {
        int col = t & 127, half = t >> 7;
        int r0 = half * 32;
        float run = 0.f;
        int prev = tgtS[r0];
        bool atStart = true;
        for (int i = 0; i < 32; ++i) {
            int tg = tgtS[r0 + i];
            if (tg != prev) {
                float* dst = &agg[(size_t)prev * 128 + col];
                if (atStart) atomicAdd(dst, run);
                else *dst = run;
                run = 0.f; prev = tg; atStart = false;
            }
            run += bf2f(Cs[(r0 + i) * 132 + col]);
        }
        atomicAdd(&agg[(size_t)prev * 128 + col], run);  // touches half end
    }
}

// ---------------------------------------------------------------------------
// Update MLP + fused batch-stats. 32 nodes/block, 128 threads (2 waves).
__global__ __launch_bounds__(128) void update_kernel(
    float* __restrict__ h, const unsigned short* __restrict__ h_bf,
    const float* __restrict__ agg, const int* __restrict__ deg,
    const float* __restrict__ post,
    const unsigned short* __restrict__ W1p, const float* __restrict__ b1,
    const unsigned short* __restrict__ W2p, const float* __restrict__ b2,
    float* __restrict__ stats)
{
    __shared__ unsigned short Ms[32 * 136];
    int t = threadIdx.x;
    int n0 = blockIdx.x * 32;
    int w = t >> 6, lane = t & 63, q = lane >> 4, m = lane & 15;
    int n = n0 + w * 16 + m;

    short8 afr[9];
    {
        const short8* hn = (const short8*)(h_bf + (size_t)n * 128);
        #pragma unroll
        for (int c = 0; c < 4; ++c) afr[c] = hn[c * 4 + q];
        float ic = 1.0f / fmaxf((float)deg[n], 1.0f);
        #pragma unroll
        for (int c = 0; c < 4; ++c) {
            const float* ap = agg + (size_t)n * 128 + c * 32 + q * 8;
            short8 a;
            #pragma unroll
            for (int j = 0; j < 8; ++j) a[j] = (short)f2bf(ap[j] * ic);
            afr[4 + c] = a;
        }
        short8 a8;
        #pragma unroll
        for (int j = 0; j < 8; ++j) a8[j] = 0;
        if (q == 0) a8[0] = (short)f2bf(post[n]);  // k=256
        afr[8] = a8;
    }

    floatx4 acc[8] = {};
    #pragma unroll
    for (int c = 0; c < 9; ++c) {
        const short8* Bp = (const short8*)(W1p) + (size_t)(c * 8) * 64 + lane;
        #pragma unroll
        for (int t8 = 0; t8 < 8; ++t8) {
            short8 b = Bp[t8 * 64];
            acc[t8] = __builtin_amdgcn_mfma_f32_16x16x32_bf16(afr[c], b, acc[t8], 0, 0, 0);
        }
    }
    #pragma unroll
    for (int t8 = 0; t8 < 8; ++t8) {
        float bv = b1[t8 * 16 + m];
        #pragma unroll
        for (int r = 0; r < 4; ++r)
            Ms[(w * 16 + q * 4 + r) * 136 + t8 * 16 + m] = f2bf(swishf(acc[t8][r] + bv));
    }
    __syncthreads();
    short8 a2[4];
    #pragma unroll
    for (int c = 0; c < 4; ++c)
        a2[c] = *(const short8*)(&Ms[(w * 16 + m) * 136 + c * 32 + q * 8]);

    floatx4 acc2[8] = {};
    #pragma unroll
    for (int c = 0; c < 4; ++c) {
        const short8* Bp = (const short8*)(W2p) + (size_t)(c * 8) * 64 + lane;
        #pragma unroll
        for (int t8 = 0; t8 < 8; ++t8) {
            short8 b = Bp[t8 * 64];
            acc2[t8] = __builtin_amdgcn_mfma_f32_16x16x32_bf16(a2[c], b, acc2[t8], 0, 0, 0);
        }
    }
    int bidx = n0 >> 12;
    #pragma unroll
    for (int t8 = 0; t8 < 8; ++t8) {
        float bv = b2[t8 * 16 + m];
        float s = 0.f, s2 = 0.f;
        #pragma unroll
        for (int r = 0; r < 4; ++r) {
            size_t idx = (size_t)(n0 + w * 16 + q * 4 + r) * 128 + t8 * 16 + m;
            float hv = h[idx] + swishf(acc2[t8][r] + bv);
            h[idx] = hv;
            s += hv; s2 += hv * hv;
        }
        s  += __shfl_xor(s, 16);  s  += __shfl_xor(s, 32);
        s2 += __shfl_xor(s2, 16); s2 += __shfl_xor(s2, 32);
        if (q == 0) {
            atomicAdd(&stats[bidx * 128 + t8 * 16 + m], s);
            atomicAdd(&stats[(NB + bidx) * 128 + t8 * 16 + m], s2);
        }
    }
}

// ---------------------------------------------------------------------------
// Norm, float4-vectorized: thread handles 4 channels.
__global__ __launch_bounds__(256) void norm_kernel(float* __restrict__ h,
                                                   unsigned short* __restrict__ h_bf,
                                                   const float* __restrict__ stats) {
    size_t id = (size_t)blockIdx.x * 256 + threadIdx.x;  // over N*32
    int n = (int)(id >> 5), c4 = (int)(id & 31) * 4;
    int b = n >> 12;
    float4 mn = *(const float4*)&stats[b * 128 + c4];
    float4 sq = *(const float4*)&stats[(NB + b) * 128 + c4];
    float4 v = *(const float4*)&h[(size_t)n * 128 + c4];
    float4 r;
    float m0 = mn.x * (1.f / 4096.f), m1 = mn.y * (1.f / 4096.f);
    float m2 = mn.z * (1.f / 4096.f), m3 = mn.w * (1.f / 4096.f);
    r.x = (v.x - m0) * rsqrtf(sq.x * (1.f / 4096.f) - m0 * m0 + 1e-5f);
    r.y = (v.y - m1) * rsqrtf(sq.y * (1.f / 4096.f) - m1 * m1 + 1e-5f);
    r.z = (v.z - m2) * rsqrtf(sq.z * (1.f / 4096.f) - m2 * m2 + 1e-5f);
    r.w = (v.w - m3) * rsqrtf(sq.w * (1.f / 4096.f) - m3 * m3 + 1e-5f);
    *(float4*)&h[(size_t)n * 128 + c4] = r;
    uint2 pk;
    pk.x = (unsigned)f2bf(r.x) | ((unsigned)f2bf(r.y) << 16);
    pk.y = (unsigned)f2bf(r.z) | ((unsigned)f2bf(r.w) << 16);
    *(uint2*)(h_bf + (size_t)n * 128 + c4) = pk;
}

// ---------------------------------------------------------------------------
__global__ __launch_bounds__(64) void conv_kernel(
    const float* __restrict__ h, const float* __restrict__ u,
    const float* __restrict__ Wc1, const float* __restrict__ bc1,
    const float* __restrict__ Wc2, const float* __restrict__ bc2,
    float* __restrict__ out)
{
    __shared__ float hs[128];
    __shared__ float c1[8 * 38];
    int n = blockIdx.x;
    int t = threadIdx.x;
    hs[t] = h[(size_t)n * 128 + t];
    hs[t + 64] = h[(size_t)n * 128 + t + 64];
    __syncthreads();
    for (int idx = t; idx < 304; idx += 64) {
        int o = idx / 38, p = idx % 38;
        float s = bc1[o];
        #pragma unroll
        for (int k = 0; k < 16; ++k) s += hs[p * 3 + k] * Wc1[o * 16 + k];
        c1[o * 38 + p] = swishf(s);
    }
    __syncthreads();
    if (t < TW) {
        float s = bc2[0];
        #pragma unroll
        for (int o = 0; o < 8; ++o)
            for (int k = 0; k < 14; ++k)
                s += c1[o * 38 + t + k] * Wc2[o * 14 + k];
        float dt_cum = (float)(t + 1) * (4.0f / 250.0f);
        out[n * TW + t] = u[n * 25 + 24] + dt_cum * s;
    }
}

// ---------------------------------------------------------------------------
extern "C" void kernel_launch(void* const* d_in, const int* in_sizes, int n_in,
                              void* d_out, int out_size, void* d_ws, size_t ws_size,
                              hipStream_t stream)
{
    const float* u   = (const float*)d_in[0];
    const float* pos = (const float*)d_in[1];
    const int*   ei  = (const int*)d_in[2];
    const float* We1 = (const float*)d_in[4];
    const float* be1 = (const float*)d_in[5];
    const float* We2 = (const float*)d_in[6];
    const float* be2 = (const float*)d_in[7];
    const float* Wm1 = (const float*)d_in[8];
    const float* bm1 = (const float*)d_in[9];
    const float* Wm2 = (const float*)d_in[10];
    const float* bm2 = (const float*)d_in[11];
    const float* Wu1 = (const float*)d_in[12];
    const float* bu1 = (const float*)d_in[13];
    const float* Wu2 = (const float*)d_in[14];
    const float* bu2 = (const float*)d_in[15];
    const float* Wc1 = (const float*)d_in[16];
    const float* bc1 = (const float*)d_in[17];
    const float* Wc2 = (const float*)d_in[18];
    const float* bc2 = (const float*)d_in[19];
    float* out = (float*)d_out;

    char* base = (char*)d_ws;
    size_t off = 0;
    auto alloc = [&](size_t bytes) -> char* {
        char* r = base + off;
        off = (off + bytes + 511) & ~(size_t)511;
        return r;
    };
    float*          h      = (float*)alloc((size_t)N_NODES * 128 * 4);
    unsigned short* h_bf   = (unsigned short*)alloc((size_t)N_NODES * 128 * 2);
    float*          agg    = (float*)alloc((size_t)N_NODES * 128 * 4);
    float*          posx   = (float*)alloc(N_NODES * 4);
    float*          post   = (float*)alloc(N_NODES * 4);
    float*          stats  = (float*)alloc(2 * NB * 128 * 4);
    int*            deg    = (int*)alloc(N_NODES * 4);
    int*            rowptr = (int*)alloc((N_NODES + 1) * 4);
    int*            cursor = (int*)alloc(N_NODES * 4);
    int*            perm   = (int*)alloc((size_t)N_EDGES * 4);
    unsigned short* Wm1p   = (unsigned short*)alloc((size_t)6 * 9 * 4096 * 2);
    unsigned short* Wm2p   = (unsigned short*)alloc((size_t)6 * 4 * 4096 * 2);
    unsigned short* Wu1p   = (unsigned short*)alloc((size_t)6 * 9 * 4096 * 2);
    unsigned short* Wu2p   = (unsigned short*)alloc((size_t)6 * 4 * 4096 * 2);
    (void)ws_size;

    const int* srcp = ei;
    const int* tgtp = ei + N_EDGES;

    init_kernel<<<N_NODES / 256, 256, 0, stream>>>(pos, posx, post);
    hipMemsetAsync(deg, 0, N_NODES * sizeof(int), stream);
    deg_kernel<<<N_EDGES / 256, 256, 0, stream>>>(tgtp, deg);
    scan_kernel<<<1, 1024, 0, stream>>>(deg, rowptr, cursor);
    scatter_kernel<<<N_EDGES / 256, 256, 0, stream>>>(tgtp, cursor, perm);
    encoder_kernel<<<N_NODES / 64, 256, 0, stream>>>(u, posx, post, We1, be1, We2, be2, h, h_bf);

    {
        int tot1 = 6 * 9 * 512;
        int tot2 = 6 * 4 * 512;
        pack_kernel<<<(tot1 + 255) / 256, 256, 0, stream>>>(Wm1, Wm1p, 283, 9, tot1);
        pack_kernel<<<(tot2 + 255) / 256, 256, 0, stream>>>(Wm2, Wm2p, 128, 4, tot2);
        pack_kernel<<<(tot1 + 255) / 256, 256, 0, stream>>>(Wu1, Wu1p, 257, 9, tot1);
        pack_kernel<<<(tot2 + 255) / 256, 256, 0, stream>>>(Wu2, Wu2p, 128, 4, tot2);
    }

    for (int l = 0; l < 6; ++l) {
        hipMemsetAsync(agg, 0, (size_t)N_NODES * 128 * sizeof(float), stream);
        hipMemsetAsync(stats, 0, 2 * NB * 128 * sizeof(float), stream);
        message_kernel<<<N_EDGES / 64, 256, 0, stream>>>(
            h_bf, u, posx, post, srcp, tgtp, perm,
            Wm1p + (size_t)l * 9 * 4096, bm1 + l * 128,
            Wm2p + (size_t)l * 4 * 4096, bm2 + l * 128, agg);
        update_kernel<<<N_NODES / 32, 128, 0, stream>>>(
            h, h_bf, agg, deg, post,
            Wu1p + (size_t)l * 9 * 4096, bu1 + l * 128,
            Wu2p + (size_t)l * 4 * 4096, bu2 + l * 128, stats);
        norm_kernel<<<(N_NODES * 32) / 256, 256, 0, stream>>>(h, h_bf, stats);
    }

    conv_kernel<<<N_NODES, 64, 0, stream>>>(h, u, Wc1, bc1, Wc2, bc2, out);
}

// Round 6
// 769.572 us; speedup vs baseline: 1.4991x; 1.1248x over previous
//
#include <hip/hip_runtime.h>
#include <stdint.h>

#define N_NODES 32768
#define N_EDGES 262144
#define NB 8
#define TW 25

typedef __attribute__((ext_vector_type(8))) short short8;
typedef __attribute__((ext_vector_type(4))) float floatx4;

__device__ __forceinline__ float swishf(float x) { return x / (1.0f + __expf(-x)); }

__device__ __forceinline__ unsigned short f2bf(float x) {
    union { float f; unsigned u; } v; v.f = x;
    unsigned r = v.u + 0x7FFFu + ((v.u >> 16) & 1u);
    return (unsigned short)(r >> 16);
}
__device__ __forceinline__ float bf2f(unsigned short b) {
    union { unsigned u; float f; } v; v.u = ((unsigned)b) << 16; return v.f;
}

// ---------------------------------------------------------------------------
__global__ void init_kernel(const float* __restrict__ pos,
                            float* __restrict__ posx, float* __restrict__ post) {
    int i = blockIdx.x * 256 + threadIdx.x;
    if (i < N_NODES) {
        post[i] = pos[i * 2 + 0] * 0.25f;
        posx[i] = pos[i * 2 + 1] * 0.0625f;
    }
}

__global__ void deg_kernel(const int* __restrict__ tgt, int* __restrict__ deg) {
    int i = blockIdx.x * 256 + threadIdx.x;
    if (i < N_EDGES) atomicAdd(&deg[tgt[i]], 1);
}

// exclusive scan of deg -> cursor, single block
__global__ __launch_bounds__(1024) void scan_kernel(const int* __restrict__ deg,
                                                    int* __restrict__ cursor) {
    __shared__ int ps[1024];
    int t = threadIdx.x;
    int base = t * 32;
    int tot = 0;
    for (int i = 0; i < 32; ++i) tot += deg[base + i];
    ps[t] = tot;
    __syncthreads();
    for (int off = 1; off < 1024; off <<= 1) {
        int v = (t >= off) ? ps[t - off] : 0;
        __syncthreads();
        ps[t] += v;
        __syncthreads();
    }
    int run = ps[t] - tot;
    for (int i = 0; i < 32; ++i) {
        cursor[base + i] = run;
        run += deg[base + i];
    }
}

// tgt-sorted edge arrays directly (no perm indirection later)
__global__ void scatter_kernel(const int* __restrict__ src, const int* __restrict__ tgt,
                               int* __restrict__ cursor,
                               int* __restrict__ src_s, int* __restrict__ tgt_s) {
    int i = blockIdx.x * 256 + threadIdx.x;
    if (i < N_EDGES) {
        int tg = tgt[i];
        int p = atomicAdd(&cursor[tg], 1);
        src_s[p] = src[i];
        tgt_s[p] = tg;
    }
}

// layer-invariant edge features, tgt-sorted order: [u_diff(25), pxd, post_t, 0x5]
__global__ __launch_bounds__(256) void ediff_kernel(
    const float* __restrict__ u, const float* __restrict__ posx,
    const float* __restrict__ post,
    const int* __restrict__ src_s, const int* __restrict__ tgt_s,
    unsigned short* __restrict__ ediff)
{
    int e = blockIdx.x * 256 + threadIdx.x;
    if (e >= N_EDGES) return;
    int s = src_s[e], g = tgt_s[e];
    unsigned short buf[32];
    #pragma unroll
    for (int k = 0; k < 25; ++k)
        buf[k] = f2bf(u[(size_t)g * 25 + k] - u[(size_t)s * 25 + k]);
    buf[25] = f2bf(posx[g] - posx[s]);
    buf[26] = f2bf(post[g]);
    #pragma unroll
    for (int k = 27; k < 32; ++k) buf[k] = 0;
    #pragma unroll
    for (int j = 0; j < 4; ++j)
        *(short8*)(ediff + (size_t)e * 32 + j * 8) = *(short8*)&buf[j * 8];
}

// ---------------------------------------------------------------------------
// Pack weight into MFMA B-frag order: frag id = ((l*Kc + c)*8 + t8)*64 + lane,
// lane holds B[k=c*32+(lane>>4)*8+j][n=t8*16+(lane&15)], j=0..7.
__global__ __launch_bounds__(256) void pack_kernel(const float* __restrict__ W,
                                                   unsigned short* __restrict__ Wp,
                                                   int Kreal, int Kc, int total) {
    int id = blockIdx.x * 256 + threadIdx.x;
    if (id >= total) return;
    int lane = id & 63;
    int t8 = (id >> 6) & 7;
    int rest = id >> 9;
    int c = rest % Kc;
    int l = rest / Kc;
    int n = t8 * 16 + (lane & 15);
    int kb = c * 32 + (lane >> 4) * 8;
    short8 v;
    #pragma unroll
    for (int j = 0; j < 8; ++j) {
        int k = kb + j;
        float x = (k < Kreal) ? W[((size_t)l * Kreal + k) * 128 + n] : 0.f;
        v[j] = (short)f2bf(x);
    }
    *(short8*)(Wp + (size_t)id * 8) = v;
}

// ---------------------------------------------------------------------------
// Encoder; also zeroes this block's agg slice (needed by layer-0 message atomics)
__global__ __launch_bounds__(256) void encoder_kernel(
    const float* __restrict__ u, const float* __restrict__ posx,
    const float* __restrict__ post,
    const float* __restrict__ We1, const float* __restrict__ be1,
    const float* __restrict__ We2, const float* __restrict__ be2,
    float* __restrict__ h, unsigned short* __restrict__ h_bf,
    float* __restrict__ agg)
{
    __shared__ __align__(16) float As[64 * 36];
    __shared__ __align__(16) float Ws[32 * 128];
    __shared__ __align__(16) float Ms[64 * 128];

    int t = threadIdx.x;
    int n0 = blockIdx.x * 64;
    int rg = t >> 5, cg = t & 31;

    {   // zero agg slice
        int r = t & 63, cseg = t >> 6;
        float4 z = make_float4(0.f, 0.f, 0.f, 0.f);
        #pragma unroll
        for (int j = 0; j < 8; ++j)
            *(float4*)(agg + (size_t)(n0 + r) * 128 + cseg * 32 + j * 4) = z;
    }

    float acc[8][4] = {};
    {
        int kk = t >> 3, cb = (t & 7) * 16;
        #pragma unroll
        for (int j = 0; j < 4; ++j) {
            float4 w = make_float4(0.f, 0.f, 0.f, 0.f);
            if (kk < 27) w = *(const float4*)&We1[kk * 128 + cb + j * 4];
            *(float4*)&Ws[kk * 128 + cb + j * 4] = w;
        }
        int el = t >> 2, kb = (t & 3) * 8, n = n0 + el;
        float v[8];
        #pragma unroll
        for (int j = 0; j < 8; ++j) {
            int k = kb + j;
            float x = 0.f;
            if (k < 25) x = u[n * 25 + k];
            else if (k == 25) x = posx[n];
            else if (k == 26) x = post[n];
            v[j] = x;
        }
        #pragma unroll
        for (int j = 0; j < 8; j += 4)
            *(float4*)&As[el * 36 + kb + j] = make_float4(v[j], v[j+1], v[j+2], v[j+3]);
        __syncthreads();
        #pragma unroll 4
        for (int kk2 = 0; kk2 < 32; ++kk2) {
            float4 b = *(const float4*)&Ws[kk2 * 128 + cg * 4];
            float a[8];
            #pragma unroll
            for (int i = 0; i < 8; ++i) a[i] = As[(rg * 8 + i) * 36 + kk2];
            #pragma unroll
            for (int i = 0; i < 8; ++i) {
                acc[i][0] += a[i] * b.x; acc[i][1] += a[i] * b.y;
                acc[i][2] += a[i] * b.z; acc[i][3] += a[i] * b.w;
            }
        }
        __syncthreads();
    }
    {
        float4 b1 = *(const float4*)&be1[cg * 4];
        #pragma unroll
        for (int i = 0; i < 8; ++i) {
            float4 m;
            m.x = swishf(acc[i][0] + b1.x);
            m.y = swishf(acc[i][1] + b1.y);
            m.z = swishf(acc[i][2] + b1.z);
            m.w = swishf(acc[i][3] + b1.w);
            *(float4*)&Ms[(rg * 8 + i) * 128 + cg * 4] = m;
        }
        __syncthreads();
    }
    float acc2[8][4] = {};
    for (int k0 = 0; k0 < 128; k0 += 32) {
        int kk = t >> 3, cb = (t & 7) * 16;
        #pragma unroll
        for (int j = 0; j < 4; ++j)
            *(float4*)&Ws[kk * 128 + cb + j * 4] =
                *(const float4*)&We2[(k0 + kk) * 128 + cb + j * 4];
        __syncthreads();
        #pragma unroll 4
        for (int kk2 = 0; kk2 < 32; ++kk2) {
            float4 b = *(const float4*)&Ws[kk2 * 128 + cg * 4];
            float a[8];
            #pragma unroll
            for (int i = 0; i < 8; ++i) a[i] = Ms[(rg * 8 + i) * 128 + (k0 + kk2)];
            #pragma unroll
            for (int i = 0; i < 8; ++i) {
                acc2[i][0] += a[i] * b.x; acc2[i][1] += a[i] * b.y;
                acc2[i][2] += a[i] * b.z; acc2[i][3] += a[i] * b.w;
            }
        }
        __syncthreads();
    }
    {
        float4 b2 = *(const float4*)&be2[cg * 4];
        #pragma unroll
        for (int i = 0; i < 8; ++i) {
            int n = n0 + rg * 8 + i;
            float4 o;
            o.x = swishf(acc2[i][0] + b2.x);
            o.y = swishf(acc2[i][1] + b2.y);
            o.z = swishf(acc2[i][2] + b2.z);
            o.w = swishf(acc2[i][3] + b2.w);
            *(float4*)&h[(size_t)n * 128 + cg * 4] = o;
            unsigned short* hb = h_bf + (size_t)n * 128 + cg * 4;
            uint2 pk;
            pk.x = (unsigned)f2bf(o.x) | ((unsigned)f2bf(o.y) << 16);
            pk.y = (unsigned)f2bf(o.z) | ((unsigned)f2bf(o.w) << 16);
            *(uint2*)hb = pk;
        }
    }
}

// ---------------------------------------------------------------------------
// Message MLP (round-3 core, round-6 staging):
//  - A rows = [h_bf[tgt] | h_bf[src] | ediff] (ediff precomputed, coalesced)
//  - block 0 zeroes stats (between norm-read l-1 and update-write l)
//  - interior-run store / boundary-run atomicAdd reduction into agg
__global__ __launch_bounds__(256, 4) void message_kernel(
    const unsigned short* __restrict__ h_bf,
    const unsigned short* __restrict__ ediff,
    const int* __restrict__ src_s, const int* __restrict__ tgt_s,
    const unsigned short* __restrict__ W1p, const float* __restrict__ b1,
    const unsigned short* __restrict__ W2p, const float* __restrict__ b2,
    float* __restrict__ agg, float* __restrict__ stats)
{
    __shared__ __align__(16) unsigned short SH[64 * 296];  // 37888 B
    __shared__ int tgtS[64];
    unsigned short* Msh = SH;          // 64 x 136 bf16
    unsigned short* Cs  = SH + 9216;   // byte 18432: 64 x 132 bf16

    int t = threadIdx.x;
    int e0 = blockIdx.x * 64;
    if (blockIdx.x == 0) {  // zero stats for this layer
        float4 z = make_float4(0.f, 0.f, 0.f, 0.f);
        *(float4*)&stats[t * 8] = z;
        *(float4*)&stats[t * 8 + 4] = z;
    }
    if (t < 64) tgtS[t] = tgt_s[e0 + t];

    // ---- stage A into LDS
    {
        int r = t & 63, cseg = t >> 6;
        int g = tgt_s[e0 + r], s = src_s[e0 + r];
        const short8* hg = (const short8*)(h_bf + (size_t)g * 128);
        const short8* hs = (const short8*)(h_bf + (size_t)s * 128);
        #pragma unroll
        for (int j = 0; j < 4; ++j) {
            int chunk = cseg * 4 + j;  // 0..15
            *(short8*)(SH + r * 296 + chunk * 8)       = hg[chunk];
            *(short8*)(SH + r * 296 + 128 + chunk * 8) = hs[chunk];
        }
        *(short8*)(SH + r * 296 + 256 + cseg * 8) =
            *(const short8*)(ediff + (size_t)(e0 + r) * 32 + cseg * 8);
    }
    __syncthreads();

    int w = t >> 6, lane = t & 63, q = lane >> 4, m = lane & 15;
    int t80 = 2 * w, t81 = 2 * w + 1;

    // ---- GEMM1: K=288 (9 chunks), wave's 2 N-tiles, 4 M-groups
    floatx4 acc0[4] = {}, acc1[4] = {};
    #pragma unroll
    for (int c = 0; c < 9; ++c) {
        short8 b0 = *(const short8*)(W1p + ((size_t)(c * 8 + t80) * 64 + lane) * 8);
        short8 b1f = *(const short8*)(W1p + ((size_t)(c * 8 + t81) * 64 + lane) * 8);
        #pragma unroll
        for (int g2 = 0; g2 < 4; ++g2) {
            short8 a = *(const short8*)(SH + (g2 * 16 + m) * 296 + c * 32 + q * 8);
            acc0[g2] = __builtin_amdgcn_mfma_f32_16x16x32_bf16(a, b0, acc0[g2], 0, 0, 0);
            acc1[g2] = __builtin_amdgcn_mfma_f32_16x16x32_bf16(a, b1f, acc1[g2], 0, 0, 0);
        }
    }
    __syncthreads();  // A region dead

    // ---- epilogue 1 -> Ms
    {
        float bv0 = b1[t80 * 16 + m], bv1 = b1[t81 * 16 + m];
        #pragma unroll
        for (int g2 = 0; g2 < 4; ++g2) {
            #pragma unroll
            for (int r = 0; r < 4; ++r) {
                int row = g2 * 16 + q * 4 + r;
                Msh[row * 136 + t80 * 16 + m] = f2bf(swishf(acc0[g2][r] + bv0));
                Msh[row * 136 + t81 * 16 + m] = f2bf(swishf(acc1[g2][r] + bv1));
            }
        }
    }
    __syncthreads();

    // ---- GEMM2: K=128 (4 chunks)
    floatx4 acc2a[4] = {}, acc2b[4] = {};
    #pragma unroll
    for (int c = 0; c < 4; ++c) {
        short8 b0 = *(const short8*)(W2p + ((size_t)(c * 8 + t80) * 64 + lane) * 8);
        short8 b1f = *(const short8*)(W2p + ((size_t)(c * 8 + t81) * 64 + lane) * 8);
        #pragma unroll
        for (int g2 = 0; g2 < 4; ++g2) {
            short8 a = *(const short8*)(Msh + (g2 * 16 + m) * 136 + c * 32 + q * 8);
            acc2a[g2] = __builtin_amdgcn_mfma_f32_16x16x32_bf16(a, b0, acc2a[g2], 0, 0, 0);
            acc2b[g2] = __builtin_amdgcn_mfma_f32_16x16x32_bf16(a, b1f, acc2b[g2], 0, 0, 0);
        }
    }
    // ---- epilogue 2 -> Cs (disjoint region)
    {
        float bv0 = b2[t80 * 16 + m], bv1 = b2[t81 * 16 + m];
        #pragma unroll
        for (int g2 = 0; g2 < 4; ++g2) {
            #pragma unroll
            for (int r = 0; r < 4; ++r) {
                int row = g2 * 16 + q * 4 + r;
                Cs[row * 132 + t80 * 16 + m] = f2bf(swishf(acc2a[g2][r] + bv0));
                Cs[row * 132 + t81 * 16 + m] = f2bf(swishf(acc2b[g2][r] + bv1));
            }
        }
    }
    __syncthreads();

    // ---- reduction: col = t&127 over rows [half*32, half*32+32)
    {
        int col = t & 127, half = t >> 7;
        int r0 = half * 32;
        float run = 0.f;
        int prev = tgtS[r0];
        bool atStart = true;
        for (int i = 0; i < 32; ++i) {
            int tg = tgtS[r0 + i];
            if (tg != prev) {
                float* dst = &agg[(size_t)prev * 128 + col];
                if (atStart) atomicAdd(dst, run);
                else *dst = run;
                run = 0.f; prev = tg; atStart = false;
            }
            run += bf2f(Cs[(r0 + i) * 132 + col]);
        }
        atomicAdd(&agg[(size_t)prev * 128 + col], run);
    }
}

// ---------------------------------------------------------------------------
// Update MLP (message-style): 64 nodes/block, 256 thr, A staged in LDS,
// wave owns 2 N-tiles over all 64 rows. Fused stats; zeroes agg slice after.
__global__ __launch_bounds__(256, 2) void update_kernel(
    float* __restrict__ h, const unsigned short* __restrict__ h_bf,
    float* __restrict__ agg, const int* __restrict__ deg,
    const float* __restrict__ post,
    const unsigned short* __restrict__ W1p, const float* __restrict__ b1,
    const unsigned short* __restrict__ W2p, const float* __restrict__ b2,
    float* __restrict__ stats)
{
    __shared__ __align__(16) unsigned short SH[64 * 296];
    unsigned short* Msh = SH;

    int t = threadIdx.x;
    int n0 = blockIdx.x * 64;

    // ---- stage A = [h_bf | agg/deg (bf16) | post-pad]
    {
        int r = t & 63, cseg = t >> 6;
        int n = n0 + r;
        const short8* hn = (const short8*)(h_bf + (size_t)n * 128);
        #pragma unroll
        for (int j = 0; j < 4; ++j) {
            int chunk = cseg * 4 + j;
            *(short8*)(SH + r * 296 + chunk * 8) = hn[chunk];
        }
        float ic = 1.0f / fmaxf((float)deg[n], 1.0f);
        #pragma unroll
        for (int j = 0; j < 4; ++j) {
            int unit = cseg * 4 + j;
            const float* ap = agg + (size_t)n * 128 + unit * 8;
            float4 v0 = *(const float4*)ap;
            float4 v1 = *(const float4*)(ap + 4);
            short8 a;
            a[0] = (short)f2bf(v0.x * ic); a[1] = (short)f2bf(v0.y * ic);
            a[2] = (short)f2bf(v0.z * ic); a[3] = (short)f2bf(v0.w * ic);
            a[4] = (short)f2bf(v1.x * ic); a[5] = (short)f2bf(v1.y * ic);
            a[6] = (short)f2bf(v1.z * ic); a[7] = (short)f2bf(v1.w * ic);
            *(short8*)(SH + r * 296 + 128 + unit * 8) = a;
        }
        short8 z;
        #pragma unroll
        for (int k = 0; k < 8; ++k) z[k] = 0;
        if (cseg == 0) z[0] = (short)f2bf(post[n]);  // k=256
        *(short8*)(SH + r * 296 + 256 + cseg * 8) = z;
    }
    __syncthreads();

    int w = t >> 6, lane = t & 63, q = lane >> 4, m = lane & 15;
    int t80 = 2 * w, t81 = 2 * w + 1;

    floatx4 acc0[4] = {}, acc1[4] = {};
    #pragma unroll
    for (int c = 0; c < 9; ++c) {
        short8 b0 = *(const short8*)(W1p + ((size_t)(c * 8 + t80) * 64 + lane) * 8);
        short8 b1f = *(const short8*)(W1p + ((size_t)(c * 8 + t81) * 64 + lane) * 8);
        #pragma unroll
        for (int g2 = 0; g2 < 4; ++g2) {
            short8 a = *(const short8*)(SH + (g2 * 16 + m) * 296 + c * 32 + q * 8);
            acc0[g2] = __builtin_amdgcn_mfma_f32_16x16x32_bf16(a, b0, acc0[g2], 0, 0, 0);
            acc1[g2] = __builtin_amdgcn_mfma_f32_16x16x32_bf16(a, b1f, acc1[g2], 0, 0, 0);
        }
    }
    __syncthreads();

    {
        float bv0 = b1[t80 * 16 + m], bv1 = b1[t81 * 16 + m];
        #pragma unroll
        for (int g2 = 0; g2 < 4; ++g2) {
            #pragma unroll
            for (int r = 0; r < 4; ++r) {
                int row = g2 * 16 + q * 4 + r;
                Msh[row * 136 + t80 * 16 + m] = f2bf(swishf(acc0[g2][r] + bv0));
                Msh[row * 136 + t81 * 16 + m] = f2bf(swishf(acc1[g2][r] + bv1));
            }
        }
    }
    __syncthreads();

    floatx4 acc2a[4] = {}, acc2b[4] = {};
    #pragma unroll
    for (int c = 0; c < 4; ++c) {
        short8 b0 = *(const short8*)(W2p + ((size_t)(c * 8 + t80) * 64 + lane) * 8);
        short8 b1f = *(const short8*)(W2p + ((size_t)(c * 8 + t81) * 64 + lane) * 8);
        #pragma unroll
        for (int g2 = 0; g2 < 4; ++g2) {
            short8 a = *(const short8*)(Msh + (g2 * 16 + m) * 136 + c * 32 + q * 8);
            acc2a[g2] = __builtin_amdgcn_mfma_f32_16x16x32_bf16(a, b0, acc2a[g2], 0, 0, 0);
            acc2b[g2] = __builtin_amdgcn_mfma_f32_16x16x32_bf16(a, b1f, acc2b[g2], 0, 0, 0);
        }
    }

    // ---- epilogue: h += swish, fused stats, zero agg slice
    int bidx = n0 >> 12;
    int col0 = t80 * 16 + m, col1 = t81 * 16 + m;
    float bv0 = b2[col0], bv1 = b2[col1];
    float s0 = 0.f, s20 = 0.f, s1 = 0.f, s21 = 0.f;
    #pragma unroll
    for (int g2 = 0; g2 < 4; ++g2) {
        #pragma unroll
        for (int r = 0; r < 4; ++r) {
            int row = g2 * 16 + q * 4 + r;
            size_t i0 = (size_t)(n0 + row) * 128 + col0;
            size_t i1 = (size_t)(n0 + row) * 128 + col1;
            float hv0 = h[i0] + swishf(acc2a[g2][r] + bv0);
            float hv1 = h[i1] + swishf(acc2b[g2][r] + bv1);
            h[i0] = hv0; h[i1] = hv1;
            s0 += hv0; s20 += hv0 * hv0;
            s1 += hv1; s21 += hv1 * hv1;
        }
    }
    s0  += __shfl_xor(s0, 16);  s0  += __shfl_xor(s0, 32);
    s20 += __shfl_xor(s20, 16); s20 += __shfl_xor(s20, 32);
    s1  += __shfl_xor(s1, 16);  s1  += __shfl_xor(s1, 32);
    s21 += __shfl_xor(s21, 16); s21 += __shfl_xor(s21, 32);
    if (q == 0) {
        atomicAdd(&stats[bidx * 128 + col0], s0);
        atomicAdd(&stats[(NB + bidx) * 128 + col0], s20);
        atomicAdd(&stats[bidx * 128 + col1], s1);
        atomicAdd(&stats[(NB + bidx) * 128 + col1], s21);
    }
    {   // zero agg slice for next layer
        int r = t & 63, cseg = t >> 6;
        float4 z = make_float4(0.f, 0.f, 0.f, 0.f);
        #pragma unroll
        for (int j = 0; j < 8; ++j)
            *(float4*)(agg + (size_t)(n0 + r) * 128 + cseg * 32 + j * 4) = z;
    }
}

// ---------------------------------------------------------------------------
__global__ __launch_bounds__(256) void norm_kernel(float* __restrict__ h,
                                                   unsigned short* __restrict__ h_bf,
                                                   const float* __restrict__ stats) {
    size_t id = (size_t)blockIdx.x * 256 + threadIdx.x;  // over N*32
    int n = (int)(id >> 5), c4 = (int)(id & 31) * 4;
    int b = n >> 12;
    float4 mn = *(const float4*)&stats[b * 128 + c4];
    float4 sq = *(const float4*)&stats[(NB + b) * 128 + c4];
    float4 v = *(const float4*)&h[(size_t)n * 128 + c4];
    float4 r;
    float m0 = mn.x * (1.f / 4096.f), m1 = mn.y * (1.f / 4096.f);
    float m2 = mn.z * (1.f / 4096.f), m3 = mn.w * (1.f / 4096.f);
    r.x = (v.x - m0) * rsqrtf(sq.x * (1.f / 4096.f) - m0 * m0 + 1e-5f);
    r.y = (v.y - m1) * rsqrtf(sq.y * (1.f / 4096.f) - m1 * m1 + 1e-5f);
    r.z = (v.z - m2) * rsqrtf(sq.z * (1.f / 4096.f) - m2 * m2 + 1e-5f);
    r.w = (v.w - m3) * rsqrtf(sq.w * (1.f / 4096.f) - m3 * m3 + 1e-5f);
    *(float4*)&h[(size_t)n * 128 + c4] = r;
    uint2 pk;
    pk.x = (unsigned)f2bf(r.x) | ((unsigned)f2bf(r.y) << 16);
    pk.y = (unsigned)f2bf(r.z) | ((unsigned)f2bf(r.w) << 16);
    *(uint2*)(h_bf + (size_t)n * 128 + c4) = pk;
}

// ---------------------------------------------------------------------------
// Conv head: 4 nodes/block, one wave per node.
__global__ __launch_bounds__(256) void conv_kernel(
    const float* __restrict__ h, const float* __restrict__ u,
    const float* __restrict__ Wc1, const float* __restrict__ bc1,
    const float* __restrict__ Wc2, const float* __restrict__ bc2,
    float* __restrict__ out)
{
    __shared__ float hs[4][128];
    __shared__ float c1[4][8 * 40];
    int w = threadIdx.x >> 6, lane = threadIdx.x & 63;
    int n = blockIdx.x * 4 + w;
    hs[w][lane] = h[(size_t)n * 128 + lane];
    hs[w][lane + 64] = h[(size_t)n * 128 + lane + 64];
    __syncthreads();
    for (int idx = lane; idx < 304; idx += 64) {
        int o = idx / 38, p = idx % 38;
        float s = bc1[o];
        #pragma unroll
        for (int k = 0; k < 16; ++k) s += hs[w][p * 3 + k] * Wc1[o * 16 + k];
        c1[w][o * 40 + p] = swishf(s);
    }
    __syncthreads();
    if (lane < TW) {
        float s = bc2[0];
        #pragma unroll
        for (int o = 0; o < 8; ++o)
            for (int k = 0; k < 14; ++k)
                s += c1[w][o * 40 + lane + k] * Wc2[o * 14 + k];
        float dt_cum = (float)(lane + 1) * (4.0f / 250.0f);
        out[n * TW + lane] = u[n * 25 + 24] + dt_cum * s;
    }
}

// ---------------------------------------------------------------------------
extern "C" void kernel_launch(void* const* d_in, const int* in_sizes, int n_in,
                              void* d_out, int out_size, void* d_ws, size_t ws_size,
                              hipStream_t stream)
{
    const float* u   = (const float*)d_in[0];
    const float* pos = (const float*)d_in[1];
    const int*   ei  = (const int*)d_in[2];
    const float* We1 = (const float*)d_in[4];
    const float* be1 = (const float*)d_in[5];
    const float* We2 = (const float*)d_in[6];
    const float* be2 = (const float*)d_in[7];
    const float* Wm1 = (const float*)d_in[8];
    const float* bm1 = (const float*)d_in[9];
    const float* Wm2 = (const float*)d_in[10];
    const float* bm2 = (const float*)d_in[11];
    const float* Wu1 = (const float*)d_in[12];
    const float* bu1 = (const float*)d_in[13];
    const float* Wu2 = (const float*)d_in[14];
    const float* bu2 = (const float*)d_in[15];
    const float* Wc1 = (const float*)d_in[16];
    const float* bc1 = (const float*)d_in[17];
    const float* Wc2 = (const float*)d_in[18];
    const float* bc2 = (const float*)d_in[19];
    float* out = (float*)d_out;

    char* base = (char*)d_ws;
    size_t off = 0;
    auto alloc = [&](size_t bytes) -> char* {
        char* r = base + off;
        off = (off + bytes + 511) & ~(size_t)511;
        return r;
    };
    float*          h      = (float*)alloc((size_t)N_NODES * 128 * 4);
    unsigned short* h_bf   = (unsigned short*)alloc((size_t)N_NODES * 128 * 2);
    float*          agg    = (float*)alloc((size_t)N_NODES * 128 * 4);
    float*          posx   = (float*)alloc(N_NODES * 4);
    float*          post   = (float*)alloc(N_NODES * 4);
    float*          stats  = (float*)alloc(2 * NB * 128 * 4);
    int*            deg    = (int*)alloc(N_NODES * 4);
    int*            cursor = (int*)alloc(N_NODES * 4);
    int*            src_s  = (int*)alloc((size_t)N_EDGES * 4);
    int*            tgt_s  = (int*)alloc((size_t)N_EDGES * 4);
    unsigned short* ediff  = (unsigned short*)alloc((size_t)N_EDGES * 32 * 2);
    unsigned short* Wm1p   = (unsigned short*)alloc((size_t)6 * 9 * 4096 * 2);
    unsigned short* Wm2p   = (unsigned short*)alloc((size_t)6 * 4 * 4096 * 2);
    unsigned short* Wu1p   = (unsigned short*)alloc((size_t)6 * 9 * 4096 * 2);
    unsigned short* Wu2p   = (unsigned short*)alloc((size_t)6 * 4 * 4096 * 2);
    (void)ws_size;

    const int* srcp = ei;
    const int* tgtp = ei + N_EDGES;

    init_kernel<<<N_NODES / 256, 256, 0, stream>>>(pos, posx, post);
    hipMemsetAsync(deg, 0, N_NODES * sizeof(int), stream);
    deg_kernel<<<N_EDGES / 256, 256, 0, stream>>>(tgtp, deg);
    scan_kernel<<<1, 1024, 0, stream>>>(deg, cursor);
    scatter_kernel<<<N_EDGES / 256, 256, 0, stream>>>(srcp, tgtp, cursor, src_s, tgt_s);
    ediff_kernel<<<N_EDGES / 256, 256, 0, stream>>>(u, posx, post, src_s, tgt_s, ediff);
    encoder_kernel<<<N_NODES / 64, 256, 0, stream>>>(u, posx, post, We1, be1, We2, be2,
                                                     h, h_bf, agg);
    {
        int tot1 = 6 * 9 * 512;
        int tot2 = 6 * 4 * 512;
        pack_kernel<<<(tot1 + 255) / 256, 256, 0, stream>>>(Wm1, Wm1p, 283, 9, tot1);
        pack_kernel<<<(tot2 + 255) / 256, 256, 0, stream>>>(Wm2, Wm2p, 128, 4, tot2);
        pack_kernel<<<(tot1 + 255) / 256, 256, 0, stream>>>(Wu1, Wu1p, 257, 9, tot1);
        pack_kernel<<<(tot2 + 255) / 256, 256, 0, stream>>>(Wu2, Wu2p, 128, 4, tot2);
    }

    for (int l = 0; l < 6; ++l) {
        message_kernel<<<N_EDGES / 64, 256, 0, stream>>>(
            h_bf, ediff, src_s, tgt_s,
            Wm1p + (size_t)l * 9 * 4096, bm1 + l * 128,
            Wm2p + (size_t)l * 4 * 4096, bm2 + l * 128, agg, stats);
        update_kernel<<<N_NODES / 64, 256, 0, stream>>>(
            h, h_bf, agg, deg, post,
            Wu1p + (size_t)l * 9 * 4096, bu1 + l * 128,
            Wu2p + (size_t)l * 4 * 4096, bu2 + l * 128, stats);
        norm_kernel<<<(N_NODES * 32) / 256, 256, 0, stream>>>(h, h_bf, stats);
    }

    conv_kernel<<<N_NODES / 4, 256, 0, stream>>>(h, u, Wc1, bc1, Wc2, bc2, out);
}